// Round 17
// baseline (262.606 us; speedup 1.0000x reference)
//
#include <hip/hip_runtime.h>
#include <stdint.h>

#define NSEQ 256
#define NRES 256
#define CM   256
#define CZ   128
#define CH   32
#define NHEAD 8
#define EPSF 1e-5f

typedef __bf16 bf16x8 __attribute__((ext_vector_type(8)));
typedef float  f32x4  __attribute__((ext_vector_type(4)));
typedef float  f32x16 __attribute__((ext_vector_type(16)));

__device__ __forceinline__ ushort f2bf(float f) {
    union { float f; uint32_t u; } v; v.f = f;
    uint32_t r = (v.u + 0x7FFFu + ((v.u >> 16) & 1u)) >> 16;
    return (ushort)r;
}
__device__ __forceinline__ uint32_t pack_bf16_rne(float lo, float hi_) {
    return (uint32_t)f2bf(lo) | ((uint32_t)f2bf(hi_) << 16);
}
__device__ __forceinline__ float bfl(uint32_t u) {
    union { uint32_t x; float f; } v; v.x = u << 16; return v.f;
}
__device__ __forceinline__ float bfh(uint32_t u) {
    union { uint32_t x; float f; } v; v.x = u & 0xffff0000u; return v.f;
}
__device__ __forceinline__ unsigned int cvt_pk_bf16(float lo, float hi_) {
    unsigned int r;
    asm("v_cvt_pk_bf16_f32 %0, %1, %2" : "=v"(r) : "v"(lo), "v"(hi_));
    return r;
}

// -------------------------------------------------- fused pre-processing
__global__ __launch_bounds__(256) void pre_kernel(const float* __restrict__ m,
                                                  const float* __restrict__ ln_m_w,
                                                  const float* __restrict__ ln_m_b,
                                                  const float* __restrict__ z,
                                                  const float* __restrict__ ln_z_w,
                                                  const float* __restrict__ ln_z_b,
                                                  const float* __restrict__ Wz,
                                                  const float* __restrict__ Wq,
                                                  const float* __restrict__ Wk,
                                                  const float* __restrict__ Wv,
                                                  const float* __restrict__ Wg,
                                                  const float* __restrict__ Wo,
                                                  ushort* __restrict__ mn,
                                                  ushort* __restrict__ biasb,
                                                  ushort* __restrict__ Wt,
                                                  ushort* __restrict__ WoT) {
    int b = blockIdx.x;
    int t = threadIdx.x;
    int lane = t & 63;

    if (b < 16384) {
        int gw = (b * 256 + t) >> 6;
        const float* row = m + (size_t)gw * 256;
        float4 x = *(const float4*)(row + lane * 4);
        float s  = x.x + x.y + x.z + x.w;
        float sq = x.x * x.x + x.y * x.y + x.z * x.z + x.w * x.w;
#pragma unroll
        for (int off = 32; off; off >>= 1) {
            s  += __shfl_xor(s, off, 64);
            sq += __shfl_xor(sq, off, 64);
        }
        float mu  = s * (1.0f / 256.0f);
        float var = sq * (1.0f / 256.0f) - mu * mu;
        float rs  = rsqrtf(var + EPSF);
        float4 wv = *(const float4*)(ln_m_w + lane * 4);
        float4 bv = *(const float4*)(ln_m_b + lane * 4);
        ushort4 o;
        o.x = f2bf((x.x - mu) * rs * wv.x + bv.x);
        o.y = f2bf((x.y - mu) * rs * wv.y + bv.y);
        o.z = f2bf((x.z - mu) * rs * wv.z + bv.z);
        o.w = f2bf((x.w - mu) * rs * wv.w + bv.w);
        *(ushort4*)(mn + (size_t)gw * 256 + lane * 4) = o;
    } else if (b < 18432) {
        int gw = ((b - 16384) * 256 + t) >> 6;
        float wz0[8], wz1[8];
#pragma unroll
        for (int h = 0; h < 8; ++h) {
            wz0[h] = Wz[(2 * lane) * 8 + h];
            wz1[h] = Wz[(2 * lane + 1) * 8 + h];
        }
        float w0 = ln_z_w[2 * lane], w1 = ln_z_w[2 * lane + 1];
        float b0 = ln_z_b[2 * lane], b1 = ln_z_b[2 * lane + 1];
        for (int row = gw; row < 65536; row += 8192) {
            float2 x = *(const float2*)(z + (size_t)row * 128 + 2 * lane);
            float s = x.x + x.y, sq = x.x * x.x + x.y * x.y;
#pragma unroll
            for (int off = 32; off; off >>= 1) {
                s  += __shfl_xor(s, off, 64);
                sq += __shfl_xor(sq, off, 64);
            }
            float mu = s * (1.0f / 128.0f);
            float rs = rsqrtf(sq * (1.0f / 128.0f) - mu * mu + EPSF);
            float z0 = (x.x - mu) * rs * w0 + b0;
            float z1 = (x.y - mu) * rs * w1 + b1;
            float acc[8];
#pragma unroll
            for (int h = 0; h < 8; ++h) acc[h] = z0 * wz0[h] + z1 * wz1[h];
            float u[4];
#pragma unroll
            for (int i = 0; i < 4; ++i) {
                float send = (lane & 1) ? acc[i] : acc[i + 4];
                float rec  = __shfl_xor(send, 1, 64);
                u[i] = ((lane & 1) ? acc[i + 4] : acc[i]) + rec;
            }
            float v2[2];
#pragma unroll
            for (int i = 0; i < 2; ++i) {
                float send = (lane & 2) ? u[i] : u[i + 2];
                float rec  = __shfl_xor(send, 2, 64);
                v2[i] = ((lane & 2) ? u[i + 2] : u[i]) + rec;
            }
            float send = (lane & 4) ? v2[0] : v2[1];
            float rec  = __shfl_xor(send, 4, 64);
            float vv = ((lane & 4) ? v2[1] : v2[0]) + rec;
            vv += __shfl_xor(vv, 8, 64);
            vv += __shfl_xor(vv, 16, 64);
            vv += __shfl_xor(vv, 32, 64);
            if (lane < 8) {
                int hh = ((lane & 1) << 2) | (lane & 2) | ((lane >> 2) & 1);
                int jc = row & 31;
                int posv = ((jc & 4) << 2) | ((jc & 24) >> 1) | (jc & 3);
                biasb[hh * 65536 + (row & ~31) + posv] = f2bf(vv);
            }
        }
    } else {
        int n = b - 18432;
        int k = t;
        if (n < 1024) {
            int nn = n & 255;
            const float* src;
            float scale = 1.0f;
            if      (n < 256) { src = Wq; scale = 0.17677669529663687f; }
            else if (n < 512) { src = Wk; }
            else if (n < 768) { src = Wv; }
            else              { src = Wg; }
            Wt[n * 256 + k] = f2bf(src[k * 256 + nn] * scale);
        } else {
            int nn = n - 1024;
            WoT[nn * 256 + k] = f2bf(Wo[k * 256 + nn]);
        }
    }
}

// ------------------------------------------------- fused projection+attention
// 2048 blocks = (s,h), 8 waves x 32 q/k rows. Identity LDS layouts (K,Q stride
// 40; V stride 264), conflict-free. Q via wave-private LDS patch. G in regs.
// Q/K/V bf16 conversion via f2bf (RNE) — r16's cvt_pk (non-RNE) cost 3.75x
// absmax. P-build keeps cvt_pk (validated r8-r14 at 1.22e-4).
__global__ __launch_bounds__(512, 4) void fused_kernel(const ushort* __restrict__ mn,
                                                       const ushort* __restrict__ Wt,
                                                       const float* __restrict__ bg,
                                                       const ushort* __restrict__ biasb,
                                                       ushort* __restrict__ GO) {
    __shared__ ushort smem[28928];  // K [0,10240) | V [10240,18688) | Q [18688,28928)
    const int t = threadIdx.x;
    const int lane = t & 63, w = t >> 6;
    const int l31 = lane & 31, hi = lane >> 5;
    const int h = blockIdx.x & 7, s = blockIdx.x >> 3;

    // mn slab fragments: rows w*32 + l31, k-chunks k2*16 + hi*8
    const ushort* mrow = mn + ((size_t)(s * 256 + w * 32 + l31)) * 256 + hi * 8;
    bf16x8 slab[16];
#pragma unroll
    for (int k2 = 0; k2 < 16; ++k2) slab[k2] = *(const bf16x8*)&mrow[k2 * 16];

    const size_t wrow = (size_t)(h * 32 + l31) * 256 + hi * 8;

    // ---- K tile: swapped mfma(WtK, slab) -> lane holds K[krow=w*32+l31][c=rho]
    {
        const ushort* wk = Wt + 256 * 256 + wrow;
        f32x16 d = {};
#pragma unroll
        for (int k2 = 0; k2 < 16; ++k2)
            d = __builtin_amdgcn_mfma_f32_32x32x16_bf16(*(const bf16x8*)&wk[k2 * 16], slab[k2], d, 0, 0, 0);
        int krow = w * 32 + l31;
#pragma unroll
        for (int g = 0; g < 4; ++g) {
            uint2 pr;
            pr.x = pack_bf16_rne(d[4 * g + 0], d[4 * g + 1]);
            pr.y = pack_bf16_rne(d[4 * g + 2], d[4 * g + 3]);
            *(uint2*)&smem[krow * 40 + g * 8 + hi * 4] = pr;   // c = 8g+4hi+{0..3}
        }
    }

    // ---- V tile: mfma(slab, WtV) -> lane holds V[krow=w*32+rho][c=l31]
    {
        const ushort* wv = Wt + 512 * 256 + wrow;
        f32x16 d = {};
#pragma unroll
        for (int k2 = 0; k2 < 16; ++k2)
            d = __builtin_amdgcn_mfma_f32_32x32x16_bf16(slab[k2], *(const bf16x8*)&wv[k2 * 16], d, 0, 0, 0);
#pragma unroll
        for (int g = 0; g < 4; ++g) {
            uint2 pr;
            pr.x = pack_bf16_rne(d[4 * g + 0], d[4 * g + 1]);
            pr.y = pack_bf16_rne(d[4 * g + 2], d[4 * g + 3]);
            *(uint2*)&smem[10240 + l31 * 264 + w * 32 + g * 8 + hi * 4] = pr;  // krow = w*32+8g+4hi+{0..3}
        }
    }

    // ---- Q tile: swapped mfma(WtQ, slab) -> wave-private patch, stride 40
    {
        const ushort* wq = Wt + wrow;
        f32x16 d = {};
#pragma unroll
        for (int k2 = 0; k2 < 16; ++k2)
            d = __builtin_amdgcn_mfma_f32_32x32x16_bf16(*(const bf16x8*)&wq[k2 * 16], slab[k2], d, 0, 0, 0);
        ushort* Qp = &smem[18688 + w * 1280 + l31 * 40];
#pragma unroll
        for (int g = 0; g < 4; ++g) {
            uint2 pr;
            pr.x = pack_bf16_rne(d[4 * g + 0], d[4 * g + 1]);
            pr.y = pack_bf16_rne(d[4 * g + 2], d[4 * g + 3]);
            *(uint2*)&Qp[g * 8 + hi * 4] = pr;                 // c = 8g+4hi+{0..3}
        }
    }

    // ---- G tile: sigmoid(mfma(WtG, slab) + bg), kept in regs (rho-layout == o)
    f32x16 gval;
    {
        const ushort* wg = Wt + 768 * 256 + wrow;
        f32x16 d = {};
#pragma unroll
        for (int k2 = 0; k2 < 16; ++k2)
            d = __builtin_amdgcn_mfma_f32_32x32x16_bf16(*(const bf16x8*)&wg[k2 * 16], slab[k2], d, 0, 0, 0);
#pragma unroll
        for (int g = 0; g < 4; ++g) {
            float4 b4 = *(const float4*)&bg[h * 32 + 8 * g + 4 * hi];
            gval[4 * g + 0] = 1.0f / (1.0f + __expf(-(d[4 * g + 0] + b4.x)));
            gval[4 * g + 1] = 1.0f / (1.0f + __expf(-(d[4 * g + 1] + b4.y)));
            gval[4 * g + 2] = 1.0f / (1.0f + __expf(-(d[4 * g + 2] + b4.z)));
            gval[4 * g + 3] = 1.0f / (1.0f + __expf(-(d[4 * g + 3] + b4.w)));
        }
    }

    __syncthreads();   // all K/V/Q LDS writes visible

    // Q fragments: identity read, q = w*32 + l31, c = chalf*16 + hi*8 + j
    const ushort* Qp = &smem[18688 + w * 1280 + l31 * 40];
    bf16x8 qf0 = *(const bf16x8*)&Qp[hi * 8];
    bf16x8 qf1 = *(const bf16x8*)&Qp[16 + hi * 8];

    const ushort* bp = biasb + (size_t)h * 65536 + (size_t)(w * 32 + l31) * 256 + hi * 16;

    float l_run = 0.f;
    f32x16 oa = {}, ob = {};

#pragma unroll 2
    for (int kt = 0; kt < 8; ++kt) {
        uint4 b0 = *(const uint4*)&bp[kt * 32];
        uint4 b1 = *(const uint4*)&bp[kt * 32 + 8];
        f32x16 sa;
        sa[0]  = bfl(b0.x); sa[1]  = bfh(b0.x);
        sa[2]  = bfl(b0.y); sa[3]  = bfh(b0.y);
        sa[4]  = bfl(b0.z); sa[5]  = bfh(b0.z);
        sa[6]  = bfl(b0.w); sa[7]  = bfh(b0.w);
        sa[8]  = bfl(b1.x); sa[9]  = bfh(b1.x);
        sa[10] = bfl(b1.y); sa[11] = bfh(b1.y);
        sa[12] = bfl(b1.z); sa[13] = bfh(b1.z);
        sa[14] = bfl(b1.w); sa[15] = bfh(b1.w);

        // QK^T swapped: identity K reads (stride 40)
        int rb = (kt * 32 + l31) * 40;
        bf16x8 kf0 = *(const bf16x8*)&smem[rb + hi * 8];
        bf16x8 kf1 = *(const bf16x8*)&smem[rb + 16 + hi * 8];
        sa = __builtin_amdgcn_mfma_f32_32x32x16_bf16(kf0, qf0, sa, 0, 0, 0);
        sa = __builtin_amdgcn_mfma_f32_32x32x16_bf16(kf1, qf1, sa, 0, 0, 0);

        // exp (no max), per-lane sum
        float ls0 = 0.f, ls1 = 0.f;
#pragma unroll
        for (int r = 0; r < 16; r += 2) {
            float p0 = __expf(sa[r]);
            float p1 = __expf(sa[r + 1]);
            sa[r] = p0; sa[r + 1] = p1;
            ls0 += p0; ls1 += p1;
        }
        l_run += ls0 + ls1;

        // P-build (validated): cvt_pk + permlane32_swap
        unsigned int w0[4], w1[4];
#pragma unroll
        for (int mm = 0; mm < 4; ++mm) {
            w0[mm] = cvt_pk_bf16(sa[4 * mm + 0], sa[4 * mm + 1]);
            w1[mm] = cvt_pk_bf16(sa[4 * mm + 2], sa[4 * mm + 3]);
        }
#pragma unroll
        for (int hh = 0; hh < 2; ++hh) {
            unsigned int F0 = w0[2 * hh], H0 = w0[2 * hh + 1];
            unsigned int F1 = w1[2 * hh], H1 = w1[2 * hh + 1];
            asm("v_permlane32_swap_b32 %0, %1" : "+v"(F0), "+v"(H0));
            asm("v_permlane32_swap_b32 %0, %1" : "+v"(F1), "+v"(H1));
            uint4 fw = make_uint4(F0, F1, H0, H1);
            bf16x8 pf = *(bf16x8*)&fw;
            // identity V read: Vt[c=l31][krow = kt*32 + hh*16 + hi*8 + j]
            bf16x8 vf = *(const bf16x8*)&smem[10240 + l31 * 264 + kt * 32 + hh * 16 + hi * 8];
            if (hh) ob = __builtin_amdgcn_mfma_f32_32x32x16_bf16(vf, pf, ob, 0, 0, 0);
            else    oa = __builtin_amdgcn_mfma_f32_32x32x16_bf16(vf, pf, oa, 0, 0, 0);
        }
    }

    l_run += __shfl_xor(l_run, 32, 64);
    float rinv = 1.0f / l_run;

    // epilogue: GO2 [h][s][q][32]; o[r] -> c = 8*(r>>2) + 4*hi + (r&3)
    const size_t grow = ((size_t)h << 21) + ((size_t)s << 13) + ((size_t)(w * 32 + l31) << 5) + hi * 4;
#pragma unroll
    for (int g = 0; g < 4; ++g) {
        float o0 = (oa[4 * g + 0] + ob[4 * g + 0]) * rinv * gval[4 * g + 0];
        float o1 = (oa[4 * g + 1] + ob[4 * g + 1]) * rinv * gval[4 * g + 1];
        float o2 = (oa[4 * g + 2] + ob[4 * g + 2]) * rinv * gval[4 * g + 2];
        float o3 = (oa[4 * g + 3] + ob[4 * g + 3]) * rinv * gval[4 * g + 3];
        ushort4 ov;
        ov.x = f2bf(o0); ov.y = f2bf(o1); ov.z = f2bf(o2); ov.w = f2bf(o3);
        *(ushort4*)&GO[grow + g * 8] = ov;
    }
}

// -------------------------------------------------------------- output GEMM
__global__ __launch_bounds__(256) void out_gemm_kernel(const ushort* __restrict__ GO,
                                                       const ushort* __restrict__ WoT,
                                                       const float* __restrict__ bo,
                                                       float* __restrict__ out) {
    __shared__ ushort SH[32768];
    int bid = blockIdx.x;
    int wid = ((bid & 7) << 7) | (bid >> 3);
    int by = wid >> 1, bx = wid & 1;
    int m0 = by << 7, n0 = bx << 7;
    int t = threadIdx.x, lane = t & 63, w = t >> 6;
    int l15 = lane & 15, l4 = lane >> 4;
    int wr = w >> 1, wc = w & 1;

    int srow  = t >> 3;
    int scolh = (((lane & 7) ^ ((lane >> 3) & 7)) << 3);
    const ushort* Ag = GO + ((size_t)(scolh >> 5) << 21) + ((size_t)(m0 + srow) << 5) + (scolh & 31);
    const ushort* Bg = WoT + (size_t)(n0 + srow) * 256 + scolh;

    auto stage = [&](int kt) {
        int k0 = kt << 6;
        int bufo = (kt & 1) << 14;
#pragma unroll
        for (int i = 0; i < 4; ++i) {
            __builtin_amdgcn_global_load_lds(
                (const __attribute__((address_space(1))) void*)(Ag + ((size_t)kt << 22) + (i << 10)),
                (__attribute__((address_space(3))) void*)&SH[bufo + t * 8 + i * 2048], 16, 0, 0);
            __builtin_amdgcn_global_load_lds(
                (const __attribute__((address_space(1))) void*)(Bg + (size_t)(i * 32) * 256 + k0),
                (__attribute__((address_space(3))) void*)&SH[bufo + 8192 + t * 8 + i * 2048], 16, 0, 0);
        }
    };

    f32x4 acc[4][4] = {};
    stage(0);

    for (int kt = 0; kt < 4; ++kt) {
        __syncthreads();
        if (kt < 3) stage(kt + 1);
        int bufo = (kt & 1) << 14;
#pragma unroll
        for (int ks = 0; ks < 2; ++ks) {
            int xr = ks * 4 + l4;
            bf16x8 af[4], bfr[4];
#pragma unroll
            for (int mi = 0; mi < 4; ++mi) {
                int row = wr * 64 + mi * 16 + l15;
                af[mi] = *(const bf16x8*)&SH[bufo + row * 64 + ((xr ^ (l15 & 7)) << 3)];
            }
#pragma unroll
            for (int ni = 0; ni < 4; ++ni) {
                int row = wc * 64 + ni * 16 + l15;
                bfr[ni] = *(const bf16x8*)&SH[bufo + 8192 + row * 64 + ((xr ^ (l15 & 7)) << 3)];
            }
#pragma unroll
            for (int mi = 0; mi < 4; ++mi)
#pragma unroll
                for (int ni = 0; ni < 4; ++ni)
                    acc[mi][ni] = __builtin_amdgcn_mfma_f32_16x16x32_bf16(af[mi], bfr[ni], acc[mi][ni], 0, 0, 0);
        }
    }

    int crow0 = m0 + wr * 64 + l4 * 4;
#pragma unroll
    for (int ni = 0; ni < 4; ++ni) {
        int col = n0 + wc * 64 + ni * 16 + l15;
        float bov = bo[col];
#pragma unroll
        for (int mi = 0; mi < 4; ++mi)
#pragma unroll
            for (int r = 0; r < 4; ++r)
                out[(size_t)(crow0 + mi * 16 + r) * 256 + col] = acc[mi][ni][r] + bov;
    }
}

// ------------------------------------------------------------------- launch
extern "C" void kernel_launch(void* const* d_in, const int* in_sizes, int n_in,
                              void* d_out, int out_size, void* d_ws, size_t ws_size,
                              hipStream_t stream) {
    const float* m      = (const float*)d_in[0];
    const float* z      = (const float*)d_in[1];
    const float* ln_m_w = (const float*)d_in[2];
    const float* ln_m_b = (const float*)d_in[3];
    const float* ln_z_w = (const float*)d_in[4];
    const float* ln_z_b = (const float*)d_in[5];
    const float* Wz     = (const float*)d_in[6];
    const float* Wq     = (const float*)d_in[7];
    const float* Wk     = (const float*)d_in[8];
    const float* Wv     = (const float*)d_in[9];
    const float* Wg     = (const float*)d_in[10];
    const float* bg     = (const float*)d_in[11];
    const float* Wo     = (const float*)d_in[12];
    const float* bo     = (const float*)d_in[13];
    float* out = (float*)d_out;

    char* ws = (char*)d_ws;
    ushort* Wt    = (ushort*)(ws + 0);            //  524288 B
    ushort* WoT   = (ushort*)(ws + 524288);       //  131072 B
    ushort* biasb = (ushort*)(ws + 655360);       // 1048576 B (region reserves 2MB)
    ushort* mn    = (ushort*)(ws + 2752512);      // 33554432 B
    ushort* GO    = (ushort*)(ws + 36306944);     // 33554432 B

    pre_kernel<<<19712, 256, 0, stream>>>(m, ln_m_w, ln_m_b, z, ln_z_w, ln_z_b,
                                          Wz, Wq, Wk, Wv, Wg, Wo,
                                          mn, biasb, Wt, WoT);
    fused_kernel<<<2048, 512, 0, stream>>>(mn, Wt, bg, biasb, GO);
    out_gemm_kernel<<<1024, 256, 0, stream>>>(GO, WoT, bo, out);
}

// Round 18
// 261.222 us; speedup vs baseline: 1.0053x; 1.0053x over previous
//
#include <hip/hip_runtime.h>
#include <stdint.h>

#define NSEQ 256
#define NRES 256
#define CM   256
#define CZ   128
#define CH   32
#define NHEAD 8
#define EPSF 1e-5f

typedef __bf16 bf16x8 __attribute__((ext_vector_type(8)));
typedef float  f32x4  __attribute__((ext_vector_type(4)));
typedef float  f32x16 __attribute__((ext_vector_type(16)));

__device__ __forceinline__ ushort f2bf(float f) {
    union { float f; uint32_t u; } v; v.f = f;
    uint32_t r = (v.u + 0x7FFFu + ((v.u >> 16) & 1u)) >> 16;
    return (ushort)r;
}
__device__ __forceinline__ uint32_t pack_bf16_rne(float lo, float hi_) {
    return (uint32_t)f2bf(lo) | ((uint32_t)f2bf(hi_) << 16);
}
__device__ __forceinline__ float bfl(uint32_t u) {
    union { uint32_t x; float f; } v; v.x = u << 16; return v.f;
}
__device__ __forceinline__ float bfh(uint32_t u) {
    union { uint32_t x; float f; } v; v.x = u & 0xffff0000u; return v.f;
}
__device__ __forceinline__ unsigned int cvt_pk_bf16(float lo, float hi_) {
    unsigned int r;
    asm("v_cvt_pk_bf16_f32 %0, %1, %2" : "=v"(r) : "v"(lo), "v"(hi_));
    return r;
}

// -------------------------------------------------- fused pre-processing
__global__ __launch_bounds__(256) void pre_kernel(const float* __restrict__ m,
                                                  const float* __restrict__ ln_m_w,
                                                  const float* __restrict__ ln_m_b,
                                                  const float* __restrict__ z,
                                                  const float* __restrict__ ln_z_w,
                                                  const float* __restrict__ ln_z_b,
                                                  const float* __restrict__ Wz,
                                                  const float* __restrict__ Wq,
                                                  const float* __restrict__ Wk,
                                                  const float* __restrict__ Wv,
                                                  const float* __restrict__ Wg,
                                                  const float* __restrict__ Wo,
                                                  ushort* __restrict__ mn,
                                                  ushort* __restrict__ biasb,
                                                  ushort* __restrict__ Wt,
                                                  ushort* __restrict__ WoT) {
    int b = blockIdx.x;
    int t = threadIdx.x;
    int lane = t & 63;

    if (b < 16384) {
        int gw = (b * 256 + t) >> 6;
        const float* row = m + (size_t)gw * 256;
        float4 x = *(const float4*)(row + lane * 4);
        float s  = x.x + x.y + x.z + x.w;
        float sq = x.x * x.x + x.y * x.y + x.z * x.z + x.w * x.w;
#pragma unroll
        for (int off = 32; off; off >>= 1) {
            s  += __shfl_xor(s, off, 64);
            sq += __shfl_xor(sq, off, 64);
        }
        float mu  = s * (1.0f / 256.0f);
        float var = sq * (1.0f / 256.0f) - mu * mu;
        float rs  = rsqrtf(var + EPSF);
        float4 wv = *(const float4*)(ln_m_w + lane * 4);
        float4 bv = *(const float4*)(ln_m_b + lane * 4);
        ushort4 o;
        o.x = f2bf((x.x - mu) * rs * wv.x + bv.x);
        o.y = f2bf((x.y - mu) * rs * wv.y + bv.y);
        o.z = f2bf((x.z - mu) * rs * wv.z + bv.z);
        o.w = f2bf((x.w - mu) * rs * wv.w + bv.w);
        *(ushort4*)(mn + (size_t)gw * 256 + lane * 4) = o;
    } else if (b < 18432) {
        int gw = ((b - 16384) * 256 + t) >> 6;
        float wz0[8], wz1[8];
#pragma unroll
        for (int h = 0; h < 8; ++h) {
            wz0[h] = Wz[(2 * lane) * 8 + h];
            wz1[h] = Wz[(2 * lane + 1) * 8 + h];
        }
        float w0 = ln_z_w[2 * lane], w1 = ln_z_w[2 * lane + 1];
        float b0 = ln_z_b[2 * lane], b1 = ln_z_b[2 * lane + 1];
        for (int row = gw; row < 65536; row += 8192) {
            float2 x = *(const float2*)(z + (size_t)row * 128 + 2 * lane);
            float s = x.x + x.y, sq = x.x * x.x + x.y * x.y;
#pragma unroll
            for (int off = 32; off; off >>= 1) {
                s  += __shfl_xor(s, off, 64);
                sq += __shfl_xor(sq, off, 64);
            }
            float mu = s * (1.0f / 128.0f);
            float rs = rsqrtf(sq * (1.0f / 128.0f) - mu * mu + EPSF);
            float z0 = (x.x - mu) * rs * w0 + b0;
            float z1 = (x.y - mu) * rs * w1 + b1;
            float acc[8];
#pragma unroll
            for (int h = 0; h < 8; ++h) acc[h] = z0 * wz0[h] + z1 * wz1[h];
            float u[4];
#pragma unroll
            for (int i = 0; i < 4; ++i) {
                float send = (lane & 1) ? acc[i] : acc[i + 4];
                float rec  = __shfl_xor(send, 1, 64);
                u[i] = ((lane & 1) ? acc[i + 4] : acc[i]) + rec;
            }
            float v2[2];
#pragma unroll
            for (int i = 0; i < 2; ++i) {
                float send = (lane & 2) ? u[i] : u[i + 2];
                float rec  = __shfl_xor(send, 2, 64);
                v2[i] = ((lane & 2) ? u[i + 2] : u[i]) + rec;
            }
            float send = (lane & 4) ? v2[0] : v2[1];
            float rec  = __shfl_xor(send, 4, 64);
            float vv = ((lane & 4) ? v2[1] : v2[0]) + rec;
            vv += __shfl_xor(vv, 8, 64);
            vv += __shfl_xor(vv, 16, 64);
            vv += __shfl_xor(vv, 32, 64);
            if (lane < 8) {
                int hh = ((lane & 1) << 2) | (lane & 2) | ((lane >> 2) & 1);
                int jc = row & 31;
                int posv = ((jc & 4) << 2) | ((jc & 24) >> 1) | (jc & 3);
                biasb[hh * 65536 + (row & ~31) + posv] = f2bf(vv);
            }
        }
    } else {
        int n = b - 18432;
        int k = t;
        if (n < 1024) {
            int nn = n & 255;
            const float* src;
            float scale = 1.0f;
            if      (n < 256) { src = Wq; scale = 0.17677669529663687f; }
            else if (n < 512) { src = Wk; }
            else if (n < 768) { src = Wv; }
            else              { src = Wg; }
            Wt[n * 256 + k] = f2bf(src[k * 256 + nn] * scale);
        } else {
            int nn = n - 1024;
            WoT[nn * 256 + k] = f2bf(Wo[k * 256 + nn]);
        }
    }
}

// ------------------------------------------------- fused projection+attention
// 2048 blocks. bid decode: r=bid&7, h=(bid>>3)&7, s=(bid>>6)*8+r.
// All 8 heads of a given s share bid%8 == s%8 -> SAME XCD, adjacent in
// dispatch -> the 128KB mn slab is fetched once per XCD L2 (r17: h=bid&7 put
// the 8 same-s blocks on 8 different XCDs -> 8x mn re-fetch, FETCH 134MB).
// Identity LDS layouts (K,Q stride 40; V stride 264), conflict-free.
// Q/K/V bf16 via f2bf (RNE); P-build keeps cvt_pk (validated).
__global__ __launch_bounds__(512, 4) void fused_kernel(const ushort* __restrict__ mn,
                                                       const ushort* __restrict__ Wt,
                                                       const float* __restrict__ bg,
                                                       const ushort* __restrict__ biasb,
                                                       ushort* __restrict__ GO) {
    __shared__ ushort smem[28928];  // K [0,10240) | V [10240,18688) | Q [18688,28928)
    const int t = threadIdx.x;
    const int lane = t & 63, w = t >> 6;
    const int l31 = lane & 31, hi = lane >> 5;
    const int bid = blockIdx.x;
    const int h = (bid >> 3) & 7;
    const int s = (bid >> 6) * 8 + (bid & 7);

    // mn slab fragments: rows w*32 + l31, k-chunks k2*16 + hi*8
    const ushort* mrow = mn + ((size_t)(s * 256 + w * 32 + l31)) * 256 + hi * 8;
    bf16x8 slab[16];
#pragma unroll
    for (int k2 = 0; k2 < 16; ++k2) slab[k2] = *(const bf16x8*)&mrow[k2 * 16];

    const size_t wrow = (size_t)(h * 32 + l31) * 256 + hi * 8;

    // ---- K tile: swapped mfma(WtK, slab) -> lane holds K[krow=w*32+l31][c=rho]
    {
        const ushort* wk = Wt + 256 * 256 + wrow;
        f32x16 d = {};
#pragma unroll
        for (int k2 = 0; k2 < 16; ++k2)
            d = __builtin_amdgcn_mfma_f32_32x32x16_bf16(*(const bf16x8*)&wk[k2 * 16], slab[k2], d, 0, 0, 0);
        int krow = w * 32 + l31;
#pragma unroll
        for (int g = 0; g < 4; ++g) {
            uint2 pr;
            pr.x = pack_bf16_rne(d[4 * g + 0], d[4 * g + 1]);
            pr.y = pack_bf16_rne(d[4 * g + 2], d[4 * g + 3]);
            *(uint2*)&smem[krow * 40 + g * 8 + hi * 4] = pr;   // c = 8g+4hi+{0..3}
        }
    }

    // ---- V tile: mfma(slab, WtV) -> lane holds V[krow=w*32+rho][c=l31]
    {
        const ushort* wv = Wt + 512 * 256 + wrow;
        f32x16 d = {};
#pragma unroll
        for (int k2 = 0; k2 < 16; ++k2)
            d = __builtin_amdgcn_mfma_f32_32x32x16_bf16(slab[k2], *(const bf16x8*)&wv[k2 * 16], d, 0, 0, 0);
#pragma unroll
        for (int g = 0; g < 4; ++g) {
            uint2 pr;
            pr.x = pack_bf16_rne(d[4 * g + 0], d[4 * g + 1]);
            pr.y = pack_bf16_rne(d[4 * g + 2], d[4 * g + 3]);
            *(uint2*)&smem[10240 + l31 * 264 + w * 32 + g * 8 + hi * 4] = pr;  // krow = w*32+8g+4hi+{0..3}
        }
    }

    // ---- Q tile: swapped mfma(WtQ, slab) -> wave-private patch, stride 40
    {
        const ushort* wq = Wt + wrow;
        f32x16 d = {};
#pragma unroll
        for (int k2 = 0; k2 < 16; ++k2)
            d = __builtin_amdgcn_mfma_f32_32x32x16_bf16(*(const bf16x8*)&wq[k2 * 16], slab[k2], d, 0, 0, 0);
        ushort* Qp = &smem[18688 + w * 1280 + l31 * 40];
#pragma unroll
        for (int g = 0; g < 4; ++g) {
            uint2 pr;
            pr.x = pack_bf16_rne(d[4 * g + 0], d[4 * g + 1]);
            pr.y = pack_bf16_rne(d[4 * g + 2], d[4 * g + 3]);
            *(uint2*)&Qp[g * 8 + hi * 4] = pr;                 // c = 8g+4hi+{0..3}
        }
    }

    // ---- G tile: sigmoid(mfma(WtG, slab) + bg), kept in regs (rho-layout == o)
    f32x16 gval;
    {
        const ushort* wg = Wt + 768 * 256 + wrow;
        f32x16 d = {};
#pragma unroll
        for (int k2 = 0; k2 < 16; ++k2)
            d = __builtin_amdgcn_mfma_f32_32x32x16_bf16(*(const bf16x8*)&wg[k2 * 16], slab[k2], d, 0, 0, 0);
#pragma unroll
        for (int g = 0; g < 4; ++g) {
            float4 b4 = *(const float4*)&bg[h * 32 + 8 * g + 4 * hi];
            gval[4 * g + 0] = 1.0f / (1.0f + __expf(-(d[4 * g + 0] + b4.x)));
            gval[4 * g + 1] = 1.0f / (1.0f + __expf(-(d[4 * g + 1] + b4.y)));
            gval[4 * g + 2] = 1.0f / (1.0f + __expf(-(d[4 * g + 2] + b4.z)));
            gval[4 * g + 3] = 1.0f / (1.0f + __expf(-(d[4 * g + 3] + b4.w)));
        }
    }

    __syncthreads();   // all K/V/Q LDS writes visible

    // Q fragments: identity read, q = w*32 + l31, c = chalf*16 + hi*8 + j
    const ushort* Qp = &smem[18688 + w * 1280 + l31 * 40];
    bf16x8 qf0 = *(const bf16x8*)&Qp[hi * 8];
    bf16x8 qf1 = *(const bf16x8*)&Qp[16 + hi * 8];

    const ushort* bp = biasb + (size_t)h * 65536 + (size_t)(w * 32 + l31) * 256 + hi * 16;

    float l_run = 0.f;
    f32x16 oa = {}, ob = {};

#pragma unroll 2
    for (int kt = 0; kt < 8; ++kt) {
        uint4 b0 = *(const uint4*)&bp[kt * 32];
        uint4 b1 = *(const uint4*)&bp[kt * 32 + 8];
        f32x16 sa;
        sa[0]  = bfl(b0.x); sa[1]  = bfh(b0.x);
        sa[2]  = bfl(b0.y); sa[3]  = bfh(b0.y);
        sa[4]  = bfl(b0.z); sa[5]  = bfh(b0.z);
        sa[6]  = bfl(b0.w); sa[7]  = bfh(b0.w);
        sa[8]  = bfl(b1.x); sa[9]  = bfh(b1.x);
        sa[10] = bfl(b1.y); sa[11] = bfh(b1.y);
        sa[12] = bfl(b1.z); sa[13] = bfh(b1.z);
        sa[14] = bfl(b1.w); sa[15] = bfh(b1.w);

        // QK^T swapped: identity K reads (stride 40)
        int rb = (kt * 32 + l31) * 40;
        bf16x8 kf0 = *(const bf16x8*)&smem[rb + hi * 8];
        bf16x8 kf1 = *(const bf16x8*)&smem[rb + 16 + hi * 8];
        sa = __builtin_amdgcn_mfma_f32_32x32x16_bf16(kf0, qf0, sa, 0, 0, 0);
        sa = __builtin_amdgcn_mfma_f32_32x32x16_bf16(kf1, qf1, sa, 0, 0, 0);

        // exp (no max), per-lane sum
        float ls0 = 0.f, ls1 = 0.f;
#pragma unroll
        for (int r = 0; r < 16; r += 2) {
            float p0 = __expf(sa[r]);
            float p1 = __expf(sa[r + 1]);
            sa[r] = p0; sa[r + 1] = p1;
            ls0 += p0; ls1 += p1;
        }
        l_run += ls0 + ls1;

        // P-build (validated): cvt_pk + permlane32_swap
        unsigned int w0[4], w1[4];
#pragma unroll
        for (int mm = 0; mm < 4; ++mm) {
            w0[mm] = cvt_pk_bf16(sa[4 * mm + 0], sa[4 * mm + 1]);
            w1[mm] = cvt_pk_bf16(sa[4 * mm + 2], sa[4 * mm + 3]);
        }
#pragma unroll
        for (int hh = 0; hh < 2; ++hh) {
            unsigned int F0 = w0[2 * hh], H0 = w0[2 * hh + 1];
            unsigned int F1 = w1[2 * hh], H1 = w1[2 * hh + 1];
            asm("v_permlane32_swap_b32 %0, %1" : "+v"(F0), "+v"(H0));
            asm("v_permlane32_swap_b32 %0, %1" : "+v"(F1), "+v"(H1));
            uint4 fw = make_uint4(F0, F1, H0, H1);
            bf16x8 pf = *(bf16x8*)&fw;
            // identity V read: Vt[c=l31][krow = kt*32 + hh*16 + hi*8 + j]
            bf16x8 vf = *(const bf16x8*)&smem[10240 + l31 * 264 + kt * 32 + hh * 16 + hi * 8];
            if (hh) ob = __builtin_amdgcn_mfma_f32_32x32x16_bf16(vf, pf, ob, 0, 0, 0);
            else    oa = __builtin_amdgcn_mfma_f32_32x32x16_bf16(vf, pf, oa, 0, 0, 0);
        }
    }

    l_run += __shfl_xor(l_run, 32, 64);
    float rinv = 1.0f / l_run;

    // epilogue: GO2 [h][s][q][32]; o[r] -> c = 8*(r>>2) + 4*hi + (r&3)
    const size_t grow = ((size_t)h << 21) + ((size_t)s << 13) + ((size_t)(w * 32 + l31) << 5) + hi * 4;
#pragma unroll
    for (int g = 0; g < 4; ++g) {
        float o0 = (oa[4 * g + 0] + ob[4 * g + 0]) * rinv * gval[4 * g + 0];
        float o1 = (oa[4 * g + 1] + ob[4 * g + 1]) * rinv * gval[4 * g + 1];
        float o2 = (oa[4 * g + 2] + ob[4 * g + 2]) * rinv * gval[4 * g + 2];
        float o3 = (oa[4 * g + 3] + ob[4 * g + 3]) * rinv * gval[4 * g + 3];
        ushort4 ov;
        ov.x = f2bf(o0); ov.y = f2bf(o1); ov.z = f2bf(o2); ov.w = f2bf(o3);
        *(ushort4*)&GO[grow + g * 8] = ov;
    }
}

// -------------------------------------------------------------- output GEMM
__global__ __launch_bounds__(256) void out_gemm_kernel(const ushort* __restrict__ GO,
                                                       const ushort* __restrict__ WoT,
                                                       const float* __restrict__ bo,
                                                       float* __restrict__ out) {
    __shared__ ushort SH[32768];
    int bid = blockIdx.x;
    int wid = ((bid & 7) << 7) | (bid >> 3);
    int by = wid >> 1, bx = wid & 1;
    int m0 = by << 7, n0 = bx << 7;
    int t = threadIdx.x, lane = t & 63, w = t >> 6;
    int l15 = lane & 15, l4 = lane >> 4;
    int wr = w >> 1, wc = w & 1;

    int srow  = t >> 3;
    int scolh = (((lane & 7) ^ ((lane >> 3) & 7)) << 3);
    const ushort* Ag = GO + ((size_t)(scolh >> 5) << 21) + ((size_t)(m0 + srow) << 5) + (scolh & 31);
    const ushort* Bg = WoT + (size_t)(n0 + srow) * 256 + scolh;

    auto stage = [&](int kt) {
        int k0 = kt << 6;
        int bufo = (kt & 1) << 14;
#pragma unroll
        for (int i = 0; i < 4; ++i) {
            __builtin_amdgcn_global_load_lds(
                (const __attribute__((address_space(1))) void*)(Ag + ((size_t)kt << 22) + (i << 10)),
                (__attribute__((address_space(3))) void*)&SH[bufo + t * 8 + i * 2048], 16, 0, 0);
            __builtin_amdgcn_global_load_lds(
                (const __attribute__((address_space(1))) void*)(Bg + (size_t)(i * 32) * 256 + k0),
                (__attribute__((address_space(3))) void*)&SH[bufo + 8192 + t * 8 + i * 2048], 16, 0, 0);
        }
    };

    f32x4 acc[4][4] = {};
    stage(0);

    for (int kt = 0; kt < 4; ++kt) {
        __syncthreads();
        if (kt < 3) stage(kt + 1);
        int bufo = (kt & 1) << 14;
#pragma unroll
        for (int ks = 0; ks < 2; ++ks) {
            int xr = ks * 4 + l4;
            bf16x8 af[4], bfr[4];
#pragma unroll
            for (int mi = 0; mi < 4; ++mi) {
                int row = wr * 64 + mi * 16 + l15;
                af[mi] = *(const bf16x8*)&SH[bufo + row * 64 + ((xr ^ (l15 & 7)) << 3)];
            }
#pragma unroll
            for (int ni = 0; ni < 4; ++ni) {
                int row = wc * 64 + ni * 16 + l15;
                bfr[ni] = *(const bf16x8*)&SH[bufo + 8192 + row * 64 + ((xr ^ (l15 & 7)) << 3)];
            }
#pragma unroll
            for (int mi = 0; mi < 4; ++mi)
#pragma unroll
                for (int ni = 0; ni < 4; ++ni)
                    acc[mi][ni] = __builtin_amdgcn_mfma_f32_16x16x32_bf16(af[mi], bfr[ni], acc[mi][ni], 0, 0, 0);
        }
    }

    int crow0 = m0 + wr * 64 + l4 * 4;
#pragma unroll
    for (int ni = 0; ni < 4; ++ni) {
        int col = n0 + wc * 64 + ni * 16 + l15;
        float bov = bo[col];
#pragma unroll
        for (int mi = 0; mi < 4; ++mi)
#pragma unroll
            for (int r = 0; r < 4; ++r)
                out[(size_t)(crow0 + mi * 16 + r) * 256 + col] = acc[mi][ni][r] + bov;
    }
}

// ------------------------------------------------------------------- launch
extern "C" void kernel_launch(void* const* d_in, const int* in_sizes, int n_in,
                              void* d_out, int out_size, void* d_ws, size_t ws_size,
                              hipStream_t stream) {
    const float* m      = (const float*)d_in[0];
    const float* z      = (const float*)d_in[1];
    const float* ln_m_w = (const float*)d_in[2];
    const float* ln_m_b = (const float*)d_in[3];
    const float* ln_z_w = (const float*)d_in[4];
    const float* ln_z_b = (const float*)d_in[5];
    const float* Wz     = (const float*)d_in[6];
    const float* Wq     = (const float*)d_in[7];
    const float* Wk     = (const float*)d_in[8];
    const float* Wv     = (const float*)d_in[9];
    const float* Wg     = (const float*)d_in[10];
    const float* bg     = (const float*)d_in[11];
    const float* Wo     = (const float*)d_in[12];
    const float* bo     = (const float*)d_in[13];
    float* out = (float*)d_out;

    char* ws = (char*)d_ws;
    ushort* Wt    = (ushort*)(ws + 0);            //  524288 B
    ushort* WoT   = (ushort*)(ws + 524288);       //  131072 B
    ushort* biasb = (ushort*)(ws + 655360);       // 1048576 B (region reserves 2MB)
    ushort* mn    = (ushort*)(ws + 2752512);      // 33554432 B
    ushort* GO    = (ushort*)(ws + 36306944);     // 33554432 B

    pre_kernel<<<19712, 256, 0, stream>>>(m, ln_m_w, ln_m_b, z, ln_z_w, ln_z_b,
                                          Wz, Wq, Wk, Wv, Wg, Wo,
                                          mn, biasb, Wt, WoT);
    fused_kernel<<<2048, 512, 0, stream>>>(mn, Wt, bg, biasb, GO);
    out_gemm_kernel<<<1024, 256, 0, stream>>>(GO, WoT, bo, out);
}